// Round 18
// baseline (601.930 us; speedup 1.0000x reference)
//
#include <hip/hip_runtime.h>
#include <math.h>

// AlphaSegmenter. R2-R16: spill fixes, parallel preps, coalesced h layout,
// inline exp64, f32 encode + 2e-3 margin + wave-parallel f64 fix, in-scope
// butterflies, vectorized reduce_sa -> 317us. R17: decode occupancy 2->4
// blocks/CU: occupancy +7pts, dur UNCHANGED -> not occupancy-bound.
// R18: ILP instead of TLP: unroll 8 on the latency-critical global-load
//      loops (h1f/decode s-loops, h2cs/outf h-loops). FP order unchanged.
//      Live regs ~100 < cap 128 at (256,4) -> no spill expected.

#define TT 262144
#define NBT 1024   // TT/256 tile blocks
#define NBR 1024   // reduction blocks for s,a
#define MARGIN 2e-3f
#define LCAP 16384

__device__ __forceinline__ float spf32(float x) {             // softplus f32
  return fmaxf(x, 0.f) + log1pf(expf(-fabsf(x)));
}

// ---- inline f64 exp: Cody-Waite + degree-12 Horner, |x| <= 700 ----
__device__ __forceinline__ double exp64(double x) {
  const double LOG2E  = 1.4426950408889634074;
  const double LN2_HI = 6.93147180369123816490e-01;
  const double LN2_LO = 1.90821492927058770002e-10;
  double kd = rint(x * LOG2E);
  double r  = fma(-kd, LN2_HI, x);
  r = fma(-kd, LN2_LO, r);
  double p = 2.08767569878681e-9;
  p = fma(p, r, 2.505210838544172e-8);
  p = fma(p, r, 2.755731922398589e-7);
  p = fma(p, r, 2.7557319223985893e-6);
  p = fma(p, r, 2.48015873015873e-5);
  p = fma(p, r, 1.984126984126984e-4);
  p = fma(p, r, 1.388888888888889e-3);
  p = fma(p, r, 8.333333333333333e-3);
  p = fma(p, r, 4.1666666666666664e-2);
  p = fma(p, r, 1.6666666666666666e-1);
  p = fma(p, r, 0.5);
  p = fma(p, r, 1.0);
  p = fma(p, r, 1.0);
  int k = (int)kd;
  long long sb = ((long long)(k + 1023)) << 52;   // 2^k
  return p * __longlong_as_double(sb);
}

__device__ __forceinline__ double tanh64(double x) {
  double ax = fmin(fabs(x), 19.0);
  double e = exp64(2.0 * ax);
  double t = 1.0 - 2.0 / (e + 1.0);
  return x >= 0.0 ? t : -t;
}

// ---- vectorized deterministic column-sums of s[T,64], a[T,16] (f64) ----
__global__ __launch_bounds__(256) void reduce_sa(const float* __restrict__ s,
                                                 const float* __restrict__ a,
                                                 double* __restrict__ ps_s,
                                                 double* __restrict__ ps_a) {
  __shared__ double sm[256 * 4];
  int tid = threadIdx.x;
  {
    int cg = tid & 15;
    int rs = tid >> 4;
    double a0 = 0, a1 = 0, a2 = 0, a3 = 0;
    const float4* s4 = (const float4*)s;
    long row0 = (long)blockIdx.x * 16 + rs;
    long stride = (long)NBR * 16;
    for (long r = row0; r < TT; r += stride) {
      float4 v = s4[r * 16 + cg];
      a0 += (double)v.x; a1 += (double)v.y; a2 += (double)v.z; a3 += (double)v.w;
    }
    sm[tid * 4 + 0] = a0; sm[tid * 4 + 1] = a1;
    sm[tid * 4 + 2] = a2; sm[tid * 4 + 3] = a3;
    __syncthreads();
    if (tid < 64) {
      double ssum = 0.0;
#pragma unroll
      for (int r2 = 0; r2 < 16; ++r2) ssum += sm[r2 * 64 + tid];  // fixed order
      ps_s[(long)blockIdx.x * 64 + tid] = ssum;
    }
    __syncthreads();
  }
  {
    int cg = tid & 3;
    int rs = tid >> 2;
    double a0 = 0, a1 = 0, a2 = 0, a3 = 0;
    const float4* a4p = (const float4*)a;
    long row0 = (long)blockIdx.x * 64 + rs;
    long stride = (long)NBR * 64;
    for (long r = row0; r < TT; r += stride) {
      float4 v = a4p[r * 4 + cg];
      a0 += (double)v.x; a1 += (double)v.y; a2 += (double)v.z; a3 += (double)v.w;
    }
    sm[tid * 4 + 0] = a0; sm[tid * 4 + 1] = a1;
    sm[tid * 4 + 2] = a2; sm[tid * 4 + 3] = a3;
    __syncthreads();
    if (tid < 16) {
      double ssum = 0.0;
#pragma unroll
      for (int r2 = 0; r2 < 64; ++r2) ssum += sm[r2 * 16 + tid];  // fixed order
      ps_a[(long)blockIdx.x * 16 + tid] = ssum;
    }
  }
}

// ---- c1 = b1 + mean_x @ W1[80:160]; 1024 partials, 128-entry chains ----
__global__ __launch_bounds__(640) void prep1(const double* __restrict__ ps_s,
                                             const double* __restrict__ ps_a,
                                             const float* __restrict__ W1,
                                             const float* __restrict__ b1,
                                             double invT, double* __restrict__ c1) {
  __shared__ double partial[80][8];
  __shared__ double mx[80];
  int tid = threadIdx.x;
  int col = tid >> 3, sub = tid & 7;
  double ssum = 0.0;
  if (col < 64) {
#pragma unroll 8
    for (int i = 0; i < 128; ++i) ssum += ps_s[((long)sub * 128 + i) * 64 + col];
  } else {
    int c = col - 64;
#pragma unroll 8
    for (int i = 0; i < 128; ++i) ssum += ps_a[((long)sub * 128 + i) * 16 + c];
  }
  partial[col][sub] = ssum;
  __syncthreads();
  if (tid < 80) {
    double s = 0.0;
#pragma unroll
    for (int i = 0; i < 8; ++i) s += partial[tid][i];
    mx[tid] = s * invT;
  }
  __syncthreads();
  if (tid < 32) {
    double acc = (double)b1[tid];
    for (int j = 0; j < 80; ++j) acc += mx[j] * (double)W1[(80 + j) * 32 + tid];
    c1[tid] = acc;
  }
}

// ---- c2 = b2 + mean_h1 @ W2[32:64] (ps_h has NBT=1024 partials) ----
__global__ __launch_bounds__(256) void prep2(const double* __restrict__ ps,
                                             const float* __restrict__ W2,
                                             const float* __restrict__ b2,
                                             double invT, double* __restrict__ c2) {
  __shared__ double partial[32][8];
  __shared__ double mh[32];
  int tid = threadIdx.x;
  int col = tid >> 3, sub = tid & 7;
  double ssum = 0.0;
#pragma unroll
  for (int i = 0; i < 128; ++i) ssum += ps[(sub * 128 + i) * 32 + col];
  partial[col][sub] = ssum;
  __syncthreads();
  if (tid < 32) {
    double s = 0.0;
#pragma unroll
    for (int i = 0; i < 8; ++i) s += partial[tid][i];
    mh[tid] = s * invT;
  }
  __syncthreads();
  if (tid < 32) {
    double acc = (double)b2[tid];
    for (int j = 0; j < 32; ++j) acc += mh[j] * (double)W2[(32 + j) * 32 + tid];
    c2[tid] = acc;
  }
}

// ---- c3[k] = b3[32+k] + mean_h2 @ W3[32:64, 32+k], k=0..16 ----
__global__ __launch_bounds__(256) void prep3(const double* __restrict__ ps,
                                             const float* __restrict__ W3,
                                             const float* __restrict__ b3,
                                             double invT, double* __restrict__ c3) {
  __shared__ double partial[32][8];
  __shared__ double mh[32];
  int tid = threadIdx.x;
  int col = tid >> 3, sub = tid & 7;
  double ssum = 0.0;
#pragma unroll
  for (int i = 0; i < 128; ++i) ssum += ps[(sub * 128 + i) * 32 + col];
  partial[col][sub] = ssum;
  __syncthreads();
  if (tid < 32) {
    double s = 0.0;
#pragma unroll
    for (int i = 0; i < 8; ++i) s += partial[tid][i];
    mh[tid] = s * invT;
  }
  __syncthreads();
  if (tid < 17) {
    double acc = (double)b3[32 + tid];
    for (int j = 0; j < 32; ++j) acc += mh[j] * (double)W3[(32 + j) * 49 + 32 + tid];
    c3[tid] = acc;
  }
}

// h layout (f32): element (block b, col k, row r) at h[b*8192 + k*256 + r]

// ---- h1 = tanhf([s,a] @ W1[:80] + c1), f32; col-sum partials (inline) ----
__global__ __launch_bounds__(256, 4) void h1f(const float* __restrict__ s,
                                              const float* __restrict__ a,
                                              const float* __restrict__ W1,
                                              const double* __restrict__ c1,
                                              float* __restrict__ h,
                                              double* __restrict__ ps_h) {
  __shared__ float Wl[80 * 32];
  __shared__ double ws[4 * 32];
  for (int i = threadIdx.x; i < 80 * 32; i += 256) Wl[i] = W1[i];
  __syncthreads();
  long t = (long)blockIdx.x * 256 + threadIdx.x;
  float acc[32];
#pragma unroll
  for (int k = 0; k < 32; ++k) acc[k] = (float)c1[k];
  const float4* s4 = (const float4*)(s + t * 64);
#pragma unroll 8
  for (int q = 0; q < 16; ++q) {            // R18: ILP 2->8 loads in flight
    float4 v = s4[q];
    const float* w = &Wl[(q * 4) * 32];
#pragma unroll
    for (int k = 0; k < 32; ++k)
      acc[k] += v.x * w[k] + v.y * w[32 + k] + v.z * w[64 + k] + v.w * w[96 + k];
  }
  const float4* a4 = (const float4*)(a + t * 16);
#pragma unroll 4
  for (int q = 0; q < 4; ++q) {
    float4 v = a4[q];
    const float* w = &Wl[(64 + q * 4) * 32];
#pragma unroll
    for (int k = 0; k < 32; ++k)
      acc[k] += v.x * w[k] + v.y * w[32 + k] + v.z * w[64 + k] + v.w * w[96 + k];
  }
  float* o = h + (size_t)blockIdx.x * 8192 + threadIdx.x;
#pragma unroll
  for (int k = 0; k < 32; ++k) { acc[k] = tanhf(acc[k]); o[k * 256] = acc[k]; }
  int lane = threadIdx.x & 63, wave = threadIdx.x >> 6;
#pragma unroll
  for (int k = 0; k < 32; ++k) {           // in-scope f32 butterfly (no ptr!)
    float v = acc[k];
    v += __shfl_down(v, 32, 64); v += __shfl_down(v, 16, 64);
    v += __shfl_down(v, 8, 64);  v += __shfl_down(v, 4, 64);
    v += __shfl_down(v, 2, 64);  v += __shfl_down(v, 1, 64);
    if (lane == 0) ws[wave * 32 + k] = (double)v;
  }
  __syncthreads();
  if (threadIdx.x < 32) {
    double ssum = ws[threadIdx.x] + ws[32 + threadIdx.x] + ws[64 + threadIdx.x] +
                  ws[96 + threadIdx.x];
    ps_h[blockIdx.x * 32 + threadIdx.x] = ssum;
  }
}

// ---- h2 col-sums ONLY (h2 recomputed later in outf; no 33MB write) ----
__global__ __launch_bounds__(256, 4) void h2cs(const float* __restrict__ h1,
                                               const float* __restrict__ W2,
                                               const double* __restrict__ c2,
                                               double* __restrict__ ps_h) {
  __shared__ float Wl[32 * 32];
  __shared__ double ws[4 * 32];
  for (int i = threadIdx.x; i < 32 * 32; i += 256) Wl[i] = W2[i];
  __syncthreads();
  const float* x = h1 + (size_t)blockIdx.x * 8192 + threadIdx.x;
  float acc[32];
#pragma unroll
  for (int k = 0; k < 32; ++k) acc[k] = (float)c2[k];
#pragma unroll 8
  for (int j = 0; j < 32; ++j) {            // R18: ILP 4->8
    float xj = x[j * 256];
#pragma unroll
    for (int k = 0; k < 32; ++k) acc[k] += xj * Wl[j * 32 + k];
  }
#pragma unroll
  for (int k = 0; k < 32; ++k) acc[k] = tanhf(acc[k]);
  int lane = threadIdx.x & 63, wave = threadIdx.x >> 6;
#pragma unroll
  for (int k = 0; k < 32; ++k) {           // in-scope f32 butterfly (no ptr!)
    float v = acc[k];
    v += __shfl_down(v, 32, 64); v += __shfl_down(v, 16, 64);
    v += __shfl_down(v, 8, 64);  v += __shfl_down(v, 4, 64);
    v += __shfl_down(v, 2, 64);  v += __shfl_down(v, 1, 64);
    if (lane == 0) ws[wave * 32 + k] = (double)v;
  }
  __syncthreads();
  if (threadIdx.x < 32) {
    double ssum = ws[threadIdx.x] + ws[32 + threadIdx.x] + ws[64 + threadIdx.x] +
                  ws[96 + threadIdx.x];
    ps_h[blockIdx.x * 32 + threadIdx.x] = ssum;
  }
}

// ---- out: recompute h2 from h1 (bit-identical FMA order to h2cs), then
//      g (f32), l (f32), ha guess, ambiguous-row list ----
__global__ __launch_bounds__(256, 4) void outf(const float* __restrict__ h1,
                                               const float* __restrict__ W2,
                                               const double* __restrict__ c2,
                                               const float* __restrict__ W3,
                                               const double* __restrict__ c3,
                                               const float* __restrict__ u,
                                               float* __restrict__ g,
                                               float* __restrict__ lvals,
                                               float* __restrict__ ha,
                                               int* __restrict__ cnt,
                                               int* __restrict__ list) {
  __shared__ float W2l[32 * 32];
  __shared__ float W3l[32 * 17];
  for (int i = threadIdx.x; i < 32 * 32; i += 256) W2l[i] = W2[i];
  for (int i = threadIdx.x; i < 32 * 17; i += 256) {
    int j = i / 17, k = i - j * 17;
    W3l[i] = W3[j * 49 + 32 + k];
  }
  __syncthreads();
  long t = (long)blockIdx.x * 256 + threadIdx.x;
  const float* x = h1 + (size_t)blockIdx.x * 8192 + threadIdx.x;
  float h2r[32];
#pragma unroll
  for (int k = 0; k < 32; ++k) h2r[k] = (float)c2[k];
#pragma unroll 8
  for (int j = 0; j < 32; ++j) {            // R18: ILP 4->8 (same FMA order)
    float xj = x[j * 256];
#pragma unroll
    for (int k = 0; k < 32; ++k) h2r[k] += xj * W2l[j * 32 + k];
  }
#pragma unroll
  for (int k = 0; k < 32; ++k) h2r[k] = tanhf(h2r[k]);
  float acc[17];
#pragma unroll
  for (int k = 0; k < 17; ++k) acc[k] = (float)c3[k];
#pragma unroll
  for (int j = 0; j < 32; ++j) {            // FULL unroll: h2r is a reg array
    float xj = h2r[j];
#pragma unroll
    for (int k = 0; k < 17; ++k) acc[k] += xj * W3l[j * 17 + k];
  }
  float4* g4 = (float4*)(g + t * 16);
  float4 o0, o1, o2, o3;
  o0.x = acc[0];  o0.y = acc[1];  o0.z = acc[2];  o0.w = acc[3];
  o1.x = acc[4];  o1.y = acc[5];  o1.z = acc[6];  o1.w = acc[7];
  o2.x = acc[8];  o2.y = acc[9];  o2.z = acc[10]; o2.w = acc[11];
  o3.x = acc[12]; o3.y = acc[13]; o3.z = acc[14]; o3.w = acc[15];
  g4[0] = o0; g4[1] = o1; g4[2] = o2; g4[3] = o3;
  float l = acc[16];
  lvals[t] = l;
  float uu = u[t];
  // fired <=> u < sigmoid(l) <=> l > logit(u)
  float lu = (uu <= 0.f) ? -1e30f : (logf(uu) - logf(1.f - uu));
  float d = l - lu;
  ha[t] = (d > 0.f) ? 1.f : 0.f;
  if (fabsf(d) < MARGIN) {
    int i = atomicAdd(cnt, 1);
    if (i < LCAP) list[i] = (int)t;
  }
}

// ---- f64 recompute of ambiguous rows: one wave per row, no reg arrays ----
__global__ __launch_bounds__(256, 4) void fixk(const float* __restrict__ s,
                                               const float* __restrict__ a,
                                               const float* __restrict__ u,
                                               const float* __restrict__ W1,
                                               const float* __restrict__ W2,
                                               const float* __restrict__ W3,
                                               const double* __restrict__ c1,
                                               const double* __restrict__ c2,
                                               const double* __restrict__ c3,
                                               const int* __restrict__ cnt,
                                               const int* __restrict__ list,
                                               float* __restrict__ ha) {
  int n = *cnt;
  if (n > LCAP) n = LCAP;
  int lane = threadIdx.x & 63;
  int wid = (blockIdx.x * 256 + threadIdx.x) >> 6;
  const int nw = (64 * 256) >> 6;
  int col = lane & 31;
  for (int i = wid; i < n; i += nw) {
    int row = list[i];
    double acc = c1[col];
    for (int j = 0; j < 64; ++j)
      acc += (double)s[(size_t)row * 64 + j] * (double)W1[j * 32 + col];
    for (int j = 0; j < 16; ++j)
      acc += (double)a[(size_t)row * 16 + j] * (double)W1[(64 + j) * 32 + col];
    double h1v = tanh64(acc);
    double acc2 = c2[col];
    for (int j = 0; j < 32; ++j)
      acc2 += __shfl(h1v, j, 64) * (double)W2[j * 32 + col];
    double h2v = tanh64(acc2);
    double term = h2v * (double)W3[col * 49 + 48];
    term += __shfl_down(term, 16, 64);
    term += __shfl_down(term, 8, 64);
    term += __shfl_down(term, 4, 64);
    term += __shfl_down(term, 2, 64);
    term += __shfl_down(term, 1, 64);
    if (lane == 0) {
      double l = c3[16] + term;
      double lc = fmin(fmax(l, -700.0), 700.0);
      double alpha = 1.0 / (1.0 + exp64(-lc));
      ha[row] = (((double)u[row]) < alpha) ? 1.f : 0.f;
    }
  }
}

// ---- post-fix stats: lp partials + per-block last-fired ----
__global__ __launch_bounds__(256, 4) void statsk(const float* __restrict__ ha,
                                                 const float* __restrict__ lvals,
                                                 int* __restrict__ lastf,
                                                 double* __restrict__ lp_part) {
  __shared__ double sm[256];
  __shared__ unsigned long long wm[4];
  long t = (long)blockIdx.x * 256 + threadIdx.x;
  bool fired = ha[t] > 0.5f;
  float lf = lvals[t];
  sm[threadIdx.x] = (double)(fired ? -spf32(-lf) : -spf32(lf));
  unsigned long long bm = __ballot(fired ? 1 : 0);
  if ((threadIdx.x & 63) == 0) wm[threadIdx.x >> 6] = bm;
  __syncthreads();
  for (int off = 128; off > 0; off >>= 1) {
    if (threadIdx.x < off) sm[threadIdx.x] += sm[threadIdx.x + off];
    __syncthreads();
  }
  if (threadIdx.x == 0) {
    lp_part[blockIdx.x] = sm[0];
    int last = -1;
#pragma unroll
    for (int w = 3; w >= 0; --w) {
      if (last < 0 && wm[w])
        last = (int)((long)blockIdx.x * 256 + w * 64 + (63 - __builtin_clzll(wm[w])));
    }
    lastf[blockIdx.x] = last;
  }
}

// ---- exclusive max-scan over per-block last-fired indices ----
__global__ __launch_bounds__(1024) void carry_scan(const int* __restrict__ lastf,
                                                   int* __restrict__ carry, int n) {
  __shared__ int sm[1024];
  int tid = threadIdx.x;
  sm[tid] = (tid < n) ? lastf[tid] : -1;
  __syncthreads();
  for (int off = 1; off < n; off <<= 1) {
    int v = sm[tid];
    int o = (tid >= off) ? sm[tid - off] : -1;
    __syncthreads();
    sm[tid] = v > o ? v : o;
    __syncthreads();
  }
  if (tid < n) carry[tid] = (tid == 0) ? -1 : sm[tid - 1];
}

// ---- scan-combine, hard_g gather, decode MLP, logits, BCE partials ----
__global__ __launch_bounds__(256, 4) void decode_kernel(
    const float* __restrict__ s, const float* __restrict__ a, const float* __restrict__ g,
    const float* __restrict__ Wp1, const float* __restrict__ bp1, const float* __restrict__ Wp2,
    const float* __restrict__ bp2, const float* __restrict__ ha, const int* __restrict__ carry,
    float* __restrict__ logits, float* __restrict__ hardg, double* __restrict__ rc_part) {
  __shared__ float W1l[80 * 32];
  __shared__ float W2l[32 * 16];
  __shared__ int wlast[4];
  __shared__ double sm[256];
  long t = (long)blockIdx.x * 256 + threadIdx.x;
  bool fired = ha[t] > 0.5f;
  unsigned long long m = __ballot(fired ? 1 : 0);
  int wave = threadIdx.x >> 6, lane = threadIdx.x & 63;
  if (lane == 0)
    wlast[wave] = m ? (int)((long)blockIdx.x * 256 + wave * 64 + (63 - __builtin_clzll(m))) : -1;
  for (int i = threadIdx.x; i < 80 * 32; i += 256) W1l[i] = Wp1[i];
  for (int i = threadIdx.x; i < 32 * 16; i += 256) W2l[i] = Wp2[i];
  __syncthreads();
  unsigned long long pm = m & (~0ULL >> (63 - lane));
  int idx = pm ? (int)((long)blockIdx.x * 256 + wave * 64 + (63 - __builtin_clzll(pm))) : -1;
#pragma unroll
  for (int w = 0; w < 4; ++w)
    if (w < wave && wlast[w] > idx) idx = wlast[w];
  int cr = carry[blockIdx.x];
  if (cr > idx) idx = cr;
  float msk = idx >= 0 ? 1.f : 0.f;
  const float4* g4 = (const float4*)(g + (long)(idx >= 0 ? idx : 0) * 16);
  float4 v0 = g4[0], v1 = g4[1], v2 = g4[2], v3 = g4[3];
  float hg0  = msk * v0.x, hg1  = msk * v0.y, hg2  = msk * v0.z, hg3  = msk * v0.w;
  float hg4  = msk * v1.x, hg5  = msk * v1.y, hg6  = msk * v1.z, hg7  = msk * v1.w;
  float hg8  = msk * v2.x, hg9  = msk * v2.y, hg10 = msk * v2.z, hg11 = msk * v2.w;
  float hg12 = msk * v3.x, hg13 = msk * v3.y, hg14 = msk * v3.z, hg15 = msk * v3.w;
  hardg[t * 16 + 0]  = hg0;  hardg[t * 16 + 1]  = hg1;
  hardg[t * 16 + 2]  = hg2;  hardg[t * 16 + 3]  = hg3;
  hardg[t * 16 + 4]  = hg4;  hardg[t * 16 + 5]  = hg5;
  hardg[t * 16 + 6]  = hg6;  hardg[t * 16 + 7]  = hg7;
  hardg[t * 16 + 8]  = hg8;  hardg[t * 16 + 9]  = hg9;
  hardg[t * 16 + 10] = hg10; hardg[t * 16 + 11] = hg11;
  hardg[t * 16 + 12] = hg12; hardg[t * 16 + 13] = hg13;
  hardg[t * 16 + 14] = hg14; hardg[t * 16 + 15] = hg15;
  float acc[32];
#pragma unroll
  for (int k = 0; k < 32; ++k) {          // consume hg first (live-range, R6)
    float v = bp1[k];
    v += hg0  * W1l[(64 + 0)  * 32 + k];  v += hg1  * W1l[(64 + 1)  * 32 + k];
    v += hg2  * W1l[(64 + 2)  * 32 + k];  v += hg3  * W1l[(64 + 3)  * 32 + k];
    v += hg4  * W1l[(64 + 4)  * 32 + k];  v += hg5  * W1l[(64 + 5)  * 32 + k];
    v += hg6  * W1l[(64 + 6)  * 32 + k];  v += hg7  * W1l[(64 + 7)  * 32 + k];
    v += hg8  * W1l[(64 + 8)  * 32 + k];  v += hg9  * W1l[(64 + 9)  * 32 + k];
    v += hg10 * W1l[(64 + 10) * 32 + k];  v += hg11 * W1l[(64 + 11) * 32 + k];
    v += hg12 * W1l[(64 + 12) * 32 + k];  v += hg13 * W1l[(64 + 13) * 32 + k];
    v += hg14 * W1l[(64 + 14) * 32 + k];  v += hg15 * W1l[(64 + 15) * 32 + k];
    acc[k] = v;
  }
  const float4* s4 = (const float4*)(s + t * 64);
#pragma unroll 8
  for (int q = 0; q < 16; ++q) {          // R18: ILP 4->8 loads in flight
    float4 v = s4[q];
    const float* w = &W1l[(q * 4) * 32];
#pragma unroll
    for (int k = 0; k < 32; ++k)
      acc[k] += v.x * w[k] + v.y * w[32 + k] + v.z * w[64 + k] + v.w * w[96 + k];
  }
#pragma unroll
  for (int k = 0; k < 32; ++k) acc[k] = tanhf(acc[k]);
  float lg[16];
#pragma unroll
  for (int k = 0; k < 16; ++k) lg[k] = bp2[k];
#pragma unroll
  for (int j = 0; j < 32; ++j) {
    float hj = acc[j];
    const float* w = &W2l[j * 16];
#pragma unroll
    for (int k = 0; k < 16; ++k) lg[k] += hj * w[k];
  }
#pragma unroll
  for (int k = 0; k < 16; ++k) logits[t * 16 + k] = lg[k];
  const float4* a4 = (const float4*)(a + t * 16);
  double rs = 0.0;
#pragma unroll
  for (int q = 0; q < 4; ++q) {
    float4 av = a4[q];
    float l0 = lg[q * 4], l1 = lg[q * 4 + 1], l2 = lg[q * 4 + 2], l3 = lg[q * 4 + 3];
    rs += (double)(av.x * spf32(-l0) + (1.f - av.x) * spf32(l0));
    rs += (double)(av.y * spf32(-l1) + (1.f - av.y) * spf32(l1));
    rs += (double)(av.z * spf32(-l2) + (1.f - av.z) * spf32(l2));
    rs += (double)(av.w * spf32(-l3) + (1.f - av.w) * spf32(l3));
  }
  sm[threadIdx.x] = rs;
  __syncthreads();
  for (int off = 128; off > 0; off >>= 1) {
    if (threadIdx.x < off) sm[threadIdx.x] += sm[threadIdx.x + off];
    __syncthreads();
  }
  if (threadIdx.x == 0) rc_part[blockIdx.x] = sm[0];
}

// ---- loss = mean(recon) * (1 + mean(log_probs)) ----
__global__ __launch_bounds__(256) void finalize(const double* __restrict__ lp_part,
                                                const double* __restrict__ rc_part, int nb,
                                                double invT, float* __restrict__ out0) {
  __shared__ double s1[256], s2[256];
  int tid = threadIdx.x;
  double a1 = 0, a2 = 0;
  for (int i = tid; i < nb; i += 256) { a1 += lp_part[i]; a2 += rc_part[i]; }
  s1[tid] = a1; s2[tid] = a2;
  __syncthreads();
  for (int off = 128; off > 0; off >>= 1) {
    if (tid < off) { s1[tid] += s1[tid + off]; s2[tid] += s2[tid + off]; }
    __syncthreads();
  }
  if (tid == 0) {
    double R = s1[0] * invT;
    double M = s2[0] * invT / 16.0;
    out0[0] = (float)(M + R * M);
  }
}

extern "C" void kernel_launch(void* const* d_in, const int* in_sizes, int n_in,
                              void* d_out, int out_size, void* d_ws, size_t ws_size,
                              hipStream_t stream) {
  const float* s   = (const float*)d_in[0];
  const float* a   = (const float*)d_in[1];
  const float* u   = (const float*)d_in[2];
  const float* W1  = (const float*)d_in[3];
  const float* b1  = (const float*)d_in[4];
  const float* W2  = (const float*)d_in[5];
  const float* b2  = (const float*)d_in[6];
  const float* W3  = (const float*)d_in[7];
  const float* b3  = (const float*)d_in[8];
  const float* Wp1 = (const float*)d_in[9];
  const float* bp1 = (const float*)d_in[10];
  const float* Wp2 = (const float*)d_in[11];
  const float* bp2 = (const float*)d_in[12];

  const double invT = 1.0 / (double)TT;

  // workspace carve: doubles first, then 16B-aligned floats, then ints
  double* ps_s   = (double*)d_ws;                 // NBR*64
  double* ps_a   = ps_s + (size_t)NBR * 64;       // NBR*16
  double* ps_h   = ps_a + (size_t)NBR * 16;       // NBT*32
  double* c1     = ps_h + (size_t)NBT * 32;       // 32
  double* c2     = c1 + 32;                       // 32
  double* c3     = c2 + 32;                       // 24 (17 used)
  double* lp     = c3 + 24;                       // NBT
  double* rc     = lp + NBT;                      // NBT
  float*  g      = (float*)(rc + NBT);            // TT*16 (16B aligned)
  float*  h      = g + (size_t)TT * 16;           // TT*32 (f32 h1)
  float*  lvals  = h + (size_t)TT * 32;           // TT
  int*    lastf  = (int*)(lvals + TT);            // NBT
  int*    carry  = lastf + NBT;                   // NBT
  int*    cnt    = carry + NBT;                   // 4 (1 used)
  int*    list   = cnt + 4;                       // LCAP

  float* out    = (float*)d_out;
  float* loss   = out;
  float* logits = out + 1;
  float* ha     = out + 1 + (size_t)TT * 16;
  float* hg     = ha + TT;

  hipMemsetAsync((void*)cnt, 0, sizeof(int), stream);
  reduce_sa<<<NBR, 256, 0, stream>>>(s, a, ps_s, ps_a);
  prep1<<<1, 640, 0, stream>>>(ps_s, ps_a, W1, b1, invT, c1);
  h1f<<<NBT, 256, 0, stream>>>(s, a, W1, c1, h, ps_h);
  prep2<<<1, 256, 0, stream>>>(ps_h, W2, b2, invT, c2);
  h2cs<<<NBT, 256, 0, stream>>>(h, W2, c2, ps_h);
  prep3<<<1, 256, 0, stream>>>(ps_h, W3, b3, invT, c3);
  outf<<<NBT, 256, 0, stream>>>(h, W2, c2, W3, c3, u, g, lvals, ha, cnt, list);
  fixk<<<64, 256, 0, stream>>>(s, a, u, W1, W2, W3, c1, c2, c3, cnt, list, ha);
  statsk<<<NBT, 256, 0, stream>>>(ha, lvals, lastf, lp);
  carry_scan<<<1, NBT, 0, stream>>>(lastf, carry, NBT);
  decode_kernel<<<NBT, 256, 0, stream>>>(s, a, g, Wp1, bp1, Wp2, bp2, ha, carry,
                                         logits, hg, rc);
  finalize<<<1, 256, 0, stream>>>(lp, rc, NBT, invT, loss);
}

// Round 19
// 312.200 us; speedup vs baseline: 1.9280x; 1.9280x over previous
//
#include <hip/hip_runtime.h>
#include <math.h>

// AlphaSegmenter. Final form = R17 (passing, 317us).
// History: R2/R5/R10/R12-13/R18 all hit the same failure class: register
// arrays or wide unrolls exceeding the allocator's choice -> scratch spill
// -> 2-30x HBM traffic. R18's unroll-8 "ILP fix" was the fifth instance
// (h1f 490MB fetch, 337us). Rule: <=4 concurrent float4 loads on these
// ~64-reg kernels; never bound below natural VGPR; never pass reg arrays
// by pointer; full-unroll every reg-array-indexed loop.
// R17 profile: decode 67us VALU 48% / HBM 21%, occupancy changes neutral;
// 12-dispatch latency-bound plateau.

#define TT 262144
#define NBT 1024   // TT/256 tile blocks
#define NBR 1024   // reduction blocks for s,a
#define MARGIN 2e-3f
#define LCAP 16384

__device__ __forceinline__ float spf32(float x) {             // softplus f32
  return fmaxf(x, 0.f) + log1pf(expf(-fabsf(x)));
}

// ---- inline f64 exp: Cody-Waite + degree-12 Horner, |x| <= 700 ----
__device__ __forceinline__ double exp64(double x) {
  const double LOG2E  = 1.4426950408889634074;
  const double LN2_HI = 6.93147180369123816490e-01;
  const double LN2_LO = 1.90821492927058770002e-10;
  double kd = rint(x * LOG2E);
  double r  = fma(-kd, LN2_HI, x);
  r = fma(-kd, LN2_LO, r);
  double p = 2.08767569878681e-9;
  p = fma(p, r, 2.505210838544172e-8);
  p = fma(p, r, 2.755731922398589e-7);
  p = fma(p, r, 2.7557319223985893e-6);
  p = fma(p, r, 2.48015873015873e-5);
  p = fma(p, r, 1.984126984126984e-4);
  p = fma(p, r, 1.388888888888889e-3);
  p = fma(p, r, 8.333333333333333e-3);
  p = fma(p, r, 4.1666666666666664e-2);
  p = fma(p, r, 1.6666666666666666e-1);
  p = fma(p, r, 0.5);
  p = fma(p, r, 1.0);
  p = fma(p, r, 1.0);
  int k = (int)kd;
  long long sb = ((long long)(k + 1023)) << 52;   // 2^k
  return p * __longlong_as_double(sb);
}

__device__ __forceinline__ double tanh64(double x) {
  double ax = fmin(fabs(x), 19.0);
  double e = exp64(2.0 * ax);
  double t = 1.0 - 2.0 / (e + 1.0);
  return x >= 0.0 ? t : -t;
}

// ---- vectorized deterministic column-sums of s[T,64], a[T,16] (f64) ----
__global__ __launch_bounds__(256) void reduce_sa(const float* __restrict__ s,
                                                 const float* __restrict__ a,
                                                 double* __restrict__ ps_s,
                                                 double* __restrict__ ps_a) {
  __shared__ double sm[256 * 4];
  int tid = threadIdx.x;
  {
    int cg = tid & 15;
    int rs = tid >> 4;
    double a0 = 0, a1 = 0, a2 = 0, a3 = 0;
    const float4* s4 = (const float4*)s;
    long row0 = (long)blockIdx.x * 16 + rs;
    long stride = (long)NBR * 16;
    for (long r = row0; r < TT; r += stride) {
      float4 v = s4[r * 16 + cg];
      a0 += (double)v.x; a1 += (double)v.y; a2 += (double)v.z; a3 += (double)v.w;
    }
    sm[tid * 4 + 0] = a0; sm[tid * 4 + 1] = a1;
    sm[tid * 4 + 2] = a2; sm[tid * 4 + 3] = a3;
    __syncthreads();
    if (tid < 64) {
      double ssum = 0.0;
#pragma unroll
      for (int r2 = 0; r2 < 16; ++r2) ssum += sm[r2 * 64 + tid];  // fixed order
      ps_s[(long)blockIdx.x * 64 + tid] = ssum;
    }
    __syncthreads();
  }
  {
    int cg = tid & 3;
    int rs = tid >> 2;
    double a0 = 0, a1 = 0, a2 = 0, a3 = 0;
    const float4* a4p = (const float4*)a;
    long row0 = (long)blockIdx.x * 64 + rs;
    long stride = (long)NBR * 64;
    for (long r = row0; r < TT; r += stride) {
      float4 v = a4p[r * 4 + cg];
      a0 += (double)v.x; a1 += (double)v.y; a2 += (double)v.z; a3 += (double)v.w;
    }
    sm[tid * 4 + 0] = a0; sm[tid * 4 + 1] = a1;
    sm[tid * 4 + 2] = a2; sm[tid * 4 + 3] = a3;
    __syncthreads();
    if (tid < 16) {
      double ssum = 0.0;
#pragma unroll
      for (int r2 = 0; r2 < 64; ++r2) ssum += sm[r2 * 16 + tid];  // fixed order
      ps_a[(long)blockIdx.x * 16 + tid] = ssum;
    }
  }
}

// ---- c1 = b1 + mean_x @ W1[80:160]; 1024 partials, 128-entry chains ----
__global__ __launch_bounds__(640) void prep1(const double* __restrict__ ps_s,
                                             const double* __restrict__ ps_a,
                                             const float* __restrict__ W1,
                                             const float* __restrict__ b1,
                                             double invT, double* __restrict__ c1) {
  __shared__ double partial[80][8];
  __shared__ double mx[80];
  int tid = threadIdx.x;
  int col = tid >> 3, sub = tid & 7;
  double ssum = 0.0;
  if (col < 64) {
#pragma unroll 8
    for (int i = 0; i < 128; ++i) ssum += ps_s[((long)sub * 128 + i) * 64 + col];
  } else {
    int c = col - 64;
#pragma unroll 8
    for (int i = 0; i < 128; ++i) ssum += ps_a[((long)sub * 128 + i) * 16 + c];
  }
  partial[col][sub] = ssum;
  __syncthreads();
  if (tid < 80) {
    double s = 0.0;
#pragma unroll
    for (int i = 0; i < 8; ++i) s += partial[tid][i];
    mx[tid] = s * invT;
  }
  __syncthreads();
  if (tid < 32) {
    double acc = (double)b1[tid];
    for (int j = 0; j < 80; ++j) acc += mx[j] * (double)W1[(80 + j) * 32 + tid];
    c1[tid] = acc;
  }
}

// ---- c2 = b2 + mean_h1 @ W2[32:64] (ps_h has NBT=1024 partials) ----
__global__ __launch_bounds__(256) void prep2(const double* __restrict__ ps,
                                             const float* __restrict__ W2,
                                             const float* __restrict__ b2,
                                             double invT, double* __restrict__ c2) {
  __shared__ double partial[32][8];
  __shared__ double mh[32];
  int tid = threadIdx.x;
  int col = tid >> 3, sub = tid & 7;
  double ssum = 0.0;
#pragma unroll
  for (int i = 0; i < 128; ++i) ssum += ps[(sub * 128 + i) * 32 + col];
  partial[col][sub] = ssum;
  __syncthreads();
  if (tid < 32) {
    double s = 0.0;
#pragma unroll
    for (int i = 0; i < 8; ++i) s += partial[tid][i];
    mh[tid] = s * invT;
  }
  __syncthreads();
  if (tid < 32) {
    double acc = (double)b2[tid];
    for (int j = 0; j < 32; ++j) acc += mh[j] * (double)W2[(32 + j) * 32 + tid];
    c2[tid] = acc;
  }
}

// ---- c3[k] = b3[32+k] + mean_h2 @ W3[32:64, 32+k], k=0..16 ----
__global__ __launch_bounds__(256) void prep3(const double* __restrict__ ps,
                                             const float* __restrict__ W3,
                                             const float* __restrict__ b3,
                                             double invT, double* __restrict__ c3) {
  __shared__ double partial[32][8];
  __shared__ double mh[32];
  int tid = threadIdx.x;
  int col = tid >> 3, sub = tid & 7;
  double ssum = 0.0;
#pragma unroll
  for (int i = 0; i < 128; ++i) ssum += ps[(sub * 128 + i) * 32 + col];
  partial[col][sub] = ssum;
  __syncthreads();
  if (tid < 32) {
    double s = 0.0;
#pragma unroll
    for (int i = 0; i < 8; ++i) s += partial[tid][i];
    mh[tid] = s * invT;
  }
  __syncthreads();
  if (tid < 17) {
    double acc = (double)b3[32 + tid];
    for (int j = 0; j < 32; ++j) acc += mh[j] * (double)W3[(32 + j) * 49 + 32 + tid];
    c3[tid] = acc;
  }
}

// h layout (f32): element (block b, col k, row r) at h[b*8192 + k*256 + r]

// ---- h1 = tanhf([s,a] @ W1[:80] + c1), f32; col-sum partials (inline) ----
__global__ __launch_bounds__(256, 4) void h1f(const float* __restrict__ s,
                                              const float* __restrict__ a,
                                              const float* __restrict__ W1,
                                              const double* __restrict__ c1,
                                              float* __restrict__ h,
                                              double* __restrict__ ps_h) {
  __shared__ float Wl[80 * 32];
  __shared__ double ws[4 * 32];
  for (int i = threadIdx.x; i < 80 * 32; i += 256) Wl[i] = W1[i];
  __syncthreads();
  long t = (long)blockIdx.x * 256 + threadIdx.x;
  float acc[32];
#pragma unroll
  for (int k = 0; k < 32; ++k) acc[k] = (float)c1[k];
  const float4* s4 = (const float4*)(s + t * 64);
#pragma unroll 2
  for (int q = 0; q < 16; ++q) {
    float4 v = s4[q];
    const float* w = &Wl[(q * 4) * 32];
#pragma unroll
    for (int k = 0; k < 32; ++k)
      acc[k] += v.x * w[k] + v.y * w[32 + k] + v.z * w[64 + k] + v.w * w[96 + k];
  }
  const float4* a4 = (const float4*)(a + t * 16);
#pragma unroll 2
  for (int q = 0; q < 4; ++q) {
    float4 v = a4[q];
    const float* w = &Wl[(64 + q * 4) * 32];
#pragma unroll
    for (int k = 0; k < 32; ++k)
      acc[k] += v.x * w[k] + v.y * w[32 + k] + v.z * w[64 + k] + v.w * w[96 + k];
  }
  float* o = h + (size_t)blockIdx.x * 8192 + threadIdx.x;
#pragma unroll
  for (int k = 0; k < 32; ++k) { acc[k] = tanhf(acc[k]); o[k * 256] = acc[k]; }
  int lane = threadIdx.x & 63, wave = threadIdx.x >> 6;
#pragma unroll
  for (int k = 0; k < 32; ++k) {           // in-scope f32 butterfly (no ptr!)
    float v = acc[k];
    v += __shfl_down(v, 32, 64); v += __shfl_down(v, 16, 64);
    v += __shfl_down(v, 8, 64);  v += __shfl_down(v, 4, 64);
    v += __shfl_down(v, 2, 64);  v += __shfl_down(v, 1, 64);
    if (lane == 0) ws[wave * 32 + k] = (double)v;
  }
  __syncthreads();
  if (threadIdx.x < 32) {
    double ssum = ws[threadIdx.x] + ws[32 + threadIdx.x] + ws[64 + threadIdx.x] +
                  ws[96 + threadIdx.x];
    ps_h[blockIdx.x * 32 + threadIdx.x] = ssum;
  }
}

// ---- h2 col-sums ONLY (h2 recomputed later in outf; no 33MB write) ----
__global__ __launch_bounds__(256, 4) void h2cs(const float* __restrict__ h1,
                                               const float* __restrict__ W2,
                                               const double* __restrict__ c2,
                                               double* __restrict__ ps_h) {
  __shared__ float Wl[32 * 32];
  __shared__ double ws[4 * 32];
  for (int i = threadIdx.x; i < 32 * 32; i += 256) Wl[i] = W2[i];
  __syncthreads();
  const float* x = h1 + (size_t)blockIdx.x * 8192 + threadIdx.x;
  float acc[32];
#pragma unroll
  for (int k = 0; k < 32; ++k) acc[k] = (float)c2[k];
#pragma unroll 4
  for (int j = 0; j < 32; ++j) {
    float xj = x[j * 256];
#pragma unroll
    for (int k = 0; k < 32; ++k) acc[k] += xj * Wl[j * 32 + k];
  }
#pragma unroll
  for (int k = 0; k < 32; ++k) acc[k] = tanhf(acc[k]);
  int lane = threadIdx.x & 63, wave = threadIdx.x >> 6;
#pragma unroll
  for (int k = 0; k < 32; ++k) {           // in-scope f32 butterfly (no ptr!)
    float v = acc[k];
    v += __shfl_down(v, 32, 64); v += __shfl_down(v, 16, 64);
    v += __shfl_down(v, 8, 64);  v += __shfl_down(v, 4, 64);
    v += __shfl_down(v, 2, 64);  v += __shfl_down(v, 1, 64);
    if (lane == 0) ws[wave * 32 + k] = (double)v;
  }
  __syncthreads();
  if (threadIdx.x < 32) {
    double ssum = ws[threadIdx.x] + ws[32 + threadIdx.x] + ws[64 + threadIdx.x] +
                  ws[96 + threadIdx.x];
    ps_h[blockIdx.x * 32 + threadIdx.x] = ssum;
  }
}

// ---- out: recompute h2 from h1 (bit-identical FMA order to h2cs), then
//      g (f32), l (f32), ha guess, ambiguous-row list ----
__global__ __launch_bounds__(256, 4) void outf(const float* __restrict__ h1,
                                               const float* __restrict__ W2,
                                               const double* __restrict__ c2,
                                               const float* __restrict__ W3,
                                               const double* __restrict__ c3,
                                               const float* __restrict__ u,
                                               float* __restrict__ g,
                                               float* __restrict__ lvals,
                                               float* __restrict__ ha,
                                               int* __restrict__ cnt,
                                               int* __restrict__ list) {
  __shared__ float W2l[32 * 32];
  __shared__ float W3l[32 * 17];
  for (int i = threadIdx.x; i < 32 * 32; i += 256) W2l[i] = W2[i];
  for (int i = threadIdx.x; i < 32 * 17; i += 256) {
    int j = i / 17, k = i - j * 17;
    W3l[i] = W3[j * 49 + 32 + k];
  }
  __syncthreads();
  long t = (long)blockIdx.x * 256 + threadIdx.x;
  const float* x = h1 + (size_t)blockIdx.x * 8192 + threadIdx.x;
  float h2r[32];
#pragma unroll
  for (int k = 0; k < 32; ++k) h2r[k] = (float)c2[k];
#pragma unroll 4
  for (int j = 0; j < 32; ++j) {
    float xj = x[j * 256];
#pragma unroll
    for (int k = 0; k < 32; ++k) h2r[k] += xj * W2l[j * 32 + k];
  }
#pragma unroll
  for (int k = 0; k < 32; ++k) h2r[k] = tanhf(h2r[k]);
  float acc[17];
#pragma unroll
  for (int k = 0; k < 17; ++k) acc[k] = (float)c3[k];
#pragma unroll
  for (int j = 0; j < 32; ++j) {            // FULL unroll: h2r is a reg array
    float xj = h2r[j];
#pragma unroll
    for (int k = 0; k < 17; ++k) acc[k] += xj * W3l[j * 17 + k];
  }
  float4* g4 = (float4*)(g + t * 16);
  float4 o0, o1, o2, o3;
  o0.x = acc[0];  o0.y = acc[1];  o0.z = acc[2];  o0.w = acc[3];
  o1.x = acc[4];  o1.y = acc[5];  o1.z = acc[6];  o1.w = acc[7];
  o2.x = acc[8];  o2.y = acc[9];  o2.z = acc[10]; o2.w = acc[11];
  o3.x = acc[12]; o3.y = acc[13]; o3.z = acc[14]; o3.w = acc[15];
  g4[0] = o0; g4[1] = o1; g4[2] = o2; g4[3] = o3;
  float l = acc[16];
  lvals[t] = l;
  float uu = u[t];
  // fired <=> u < sigmoid(l) <=> l > logit(u)
  float lu = (uu <= 0.f) ? -1e30f : (logf(uu) - logf(1.f - uu));
  float d = l - lu;
  ha[t] = (d > 0.f) ? 1.f : 0.f;
  if (fabsf(d) < MARGIN) {
    int i = atomicAdd(cnt, 1);
    if (i < LCAP) list[i] = (int)t;
  }
}

// ---- f64 recompute of ambiguous rows: one wave per row, no reg arrays ----
__global__ __launch_bounds__(256, 4) void fixk(const float* __restrict__ s,
                                               const float* __restrict__ a,
                                               const float* __restrict__ u,
                                               const float* __restrict__ W1,
                                               const float* __restrict__ W2,
                                               const float* __restrict__ W3,
                                               const double* __restrict__ c1,
                                               const double* __restrict__ c2,
                                               const double* __restrict__ c3,
                                               const int* __restrict__ cnt,
                                               const int* __restrict__ list,
                                               float* __restrict__ ha) {
  int n = *cnt;
  if (n > LCAP) n = LCAP;
  int lane = threadIdx.x & 63;
  int wid = (blockIdx.x * 256 + threadIdx.x) >> 6;
  const int nw = (64 * 256) >> 6;
  int col = lane & 31;
  for (int i = wid; i < n; i += nw) {
    int row = list[i];
    double acc = c1[col];
    for (int j = 0; j < 64; ++j)
      acc += (double)s[(size_t)row * 64 + j] * (double)W1[j * 32 + col];
    for (int j = 0; j < 16; ++j)
      acc += (double)a[(size_t)row * 16 + j] * (double)W1[(64 + j) * 32 + col];
    double h1v = tanh64(acc);
    double acc2 = c2[col];
    for (int j = 0; j < 32; ++j)
      acc2 += __shfl(h1v, j, 64) * (double)W2[j * 32 + col];
    double h2v = tanh64(acc2);
    double term = h2v * (double)W3[col * 49 + 48];
    term += __shfl_down(term, 16, 64);
    term += __shfl_down(term, 8, 64);
    term += __shfl_down(term, 4, 64);
    term += __shfl_down(term, 2, 64);
    term += __shfl_down(term, 1, 64);
    if (lane == 0) {
      double l = c3[16] + term;
      double lc = fmin(fmax(l, -700.0), 700.0);
      double alpha = 1.0 / (1.0 + exp64(-lc));
      ha[row] = (((double)u[row]) < alpha) ? 1.f : 0.f;
    }
  }
}

// ---- post-fix stats: lp partials + per-block last-fired ----
__global__ __launch_bounds__(256, 4) void statsk(const float* __restrict__ ha,
                                                 const float* __restrict__ lvals,
                                                 int* __restrict__ lastf,
                                                 double* __restrict__ lp_part) {
  __shared__ double sm[256];
  __shared__ unsigned long long wm[4];
  long t = (long)blockIdx.x * 256 + threadIdx.x;
  bool fired = ha[t] > 0.5f;
  float lf = lvals[t];
  sm[threadIdx.x] = (double)(fired ? -spf32(-lf) : -spf32(lf));
  unsigned long long bm = __ballot(fired ? 1 : 0);
  if ((threadIdx.x & 63) == 0) wm[threadIdx.x >> 6] = bm;
  __syncthreads();
  for (int off = 128; off > 0; off >>= 1) {
    if (threadIdx.x < off) sm[threadIdx.x] += sm[threadIdx.x + off];
    __syncthreads();
  }
  if (threadIdx.x == 0) {
    lp_part[blockIdx.x] = sm[0];
    int last = -1;
#pragma unroll
    for (int w = 3; w >= 0; --w) {
      if (last < 0 && wm[w])
        last = (int)((long)blockIdx.x * 256 + w * 64 + (63 - __builtin_clzll(wm[w])));
    }
    lastf[blockIdx.x] = last;
  }
}

// ---- exclusive max-scan over per-block last-fired indices ----
__global__ __launch_bounds__(1024) void carry_scan(const int* __restrict__ lastf,
                                                   int* __restrict__ carry, int n) {
  __shared__ int sm[1024];
  int tid = threadIdx.x;
  sm[tid] = (tid < n) ? lastf[tid] : -1;
  __syncthreads();
  for (int off = 1; off < n; off <<= 1) {
    int v = sm[tid];
    int o = (tid >= off) ? sm[tid - off] : -1;
    __syncthreads();
    sm[tid] = v > o ? v : o;
    __syncthreads();
  }
  if (tid < n) carry[tid] = (tid == 0) ? -1 : sm[tid - 1];
}

// ---- scan-combine, hard_g gather, decode MLP, logits, BCE partials ----
__global__ __launch_bounds__(256, 4) void decode_kernel(
    const float* __restrict__ s, const float* __restrict__ a, const float* __restrict__ g,
    const float* __restrict__ Wp1, const float* __restrict__ bp1, const float* __restrict__ Wp2,
    const float* __restrict__ bp2, const float* __restrict__ ha, const int* __restrict__ carry,
    float* __restrict__ logits, float* __restrict__ hardg, double* __restrict__ rc_part) {
  __shared__ float W1l[80 * 32];
  __shared__ float W2l[32 * 16];
  __shared__ int wlast[4];
  __shared__ double sm[256];
  long t = (long)blockIdx.x * 256 + threadIdx.x;
  bool fired = ha[t] > 0.5f;
  unsigned long long m = __ballot(fired ? 1 : 0);
  int wave = threadIdx.x >> 6, lane = threadIdx.x & 63;
  if (lane == 0)
    wlast[wave] = m ? (int)((long)blockIdx.x * 256 + wave * 64 + (63 - __builtin_clzll(m))) : -1;
  for (int i = threadIdx.x; i < 80 * 32; i += 256) W1l[i] = Wp1[i];
  for (int i = threadIdx.x; i < 32 * 16; i += 256) W2l[i] = Wp2[i];
  __syncthreads();
  unsigned long long pm = m & (~0ULL >> (63 - lane));
  int idx = pm ? (int)((long)blockIdx.x * 256 + wave * 64 + (63 - __builtin_clzll(pm))) : -1;
#pragma unroll
  for (int w = 0; w < 4; ++w)
    if (w < wave && wlast[w] > idx) idx = wlast[w];
  int cr = carry[blockIdx.x];
  if (cr > idx) idx = cr;
  float msk = idx >= 0 ? 1.f : 0.f;
  const float4* g4 = (const float4*)(g + (long)(idx >= 0 ? idx : 0) * 16);
  float4 v0 = g4[0], v1 = g4[1], v2 = g4[2], v3 = g4[3];
  float hg0  = msk * v0.x, hg1  = msk * v0.y, hg2  = msk * v0.z, hg3  = msk * v0.w;
  float hg4  = msk * v1.x, hg5  = msk * v1.y, hg6  = msk * v1.z, hg7  = msk * v1.w;
  float hg8  = msk * v2.x, hg9  = msk * v2.y, hg10 = msk * v2.z, hg11 = msk * v2.w;
  float hg12 = msk * v3.x, hg13 = msk * v3.y, hg14 = msk * v3.z, hg15 = msk * v3.w;
  hardg[t * 16 + 0]  = hg0;  hardg[t * 16 + 1]  = hg1;
  hardg[t * 16 + 2]  = hg2;  hardg[t * 16 + 3]  = hg3;
  hardg[t * 16 + 4]  = hg4;  hardg[t * 16 + 5]  = hg5;
  hardg[t * 16 + 6]  = hg6;  hardg[t * 16 + 7]  = hg7;
  hardg[t * 16 + 8]  = hg8;  hardg[t * 16 + 9]  = hg9;
  hardg[t * 16 + 10] = hg10; hardg[t * 16 + 11] = hg11;
  hardg[t * 16 + 12] = hg12; hardg[t * 16 + 13] = hg13;
  hardg[t * 16 + 14] = hg14; hardg[t * 16 + 15] = hg15;
  float acc[32];
#pragma unroll
  for (int k = 0; k < 32; ++k) {          // consume hg first (live-range, R6)
    float v = bp1[k];
    v += hg0  * W1l[(64 + 0)  * 32 + k];  v += hg1  * W1l[(64 + 1)  * 32 + k];
    v += hg2  * W1l[(64 + 2)  * 32 + k];  v += hg3  * W1l[(64 + 3)  * 32 + k];
    v += hg4  * W1l[(64 + 4)  * 32 + k];  v += hg5  * W1l[(64 + 5)  * 32 + k];
    v += hg6  * W1l[(64 + 6)  * 32 + k];  v += hg7  * W1l[(64 + 7)  * 32 + k];
    v += hg8  * W1l[(64 + 8)  * 32 + k];  v += hg9  * W1l[(64 + 9)  * 32 + k];
    v += hg10 * W1l[(64 + 10) * 32 + k];  v += hg11 * W1l[(64 + 11) * 32 + k];
    v += hg12 * W1l[(64 + 12) * 32 + k];  v += hg13 * W1l[(64 + 13) * 32 + k];
    v += hg14 * W1l[(64 + 14) * 32 + k];  v += hg15 * W1l[(64 + 15) * 32 + k];
    acc[k] = v;
  }
  const float4* s4 = (const float4*)(s + t * 64);
#pragma unroll 4
  for (int q = 0; q < 16; ++q) {
    float4 v = s4[q];
    const float* w = &W1l[(q * 4) * 32];
#pragma unroll
    for (int k = 0; k < 32; ++k)
      acc[k] += v.x * w[k] + v.y * w[32 + k] + v.z * w[64 + k] + v.w * w[96 + k];
  }
#pragma unroll
  for (int k = 0; k < 32; ++k) acc[k] = tanhf(acc[k]);
  float lg[16];
#pragma unroll
  for (int k = 0; k < 16; ++k) lg[k] = bp2[k];
#pragma unroll
  for (int j = 0; j < 32; ++j) {
    float hj = acc[j];
    const float* w = &W2l[j * 16];
#pragma unroll
    for (int k = 0; k < 16; ++k) lg[k] += hj * w[k];
  }
#pragma unroll
  for (int k = 0; k < 16; ++k) logits[t * 16 + k] = lg[k];
  const float4* a4 = (const float4*)(a + t * 16);
  double rs = 0.0;
#pragma unroll
  for (int q = 0; q < 4; ++q) {
    float4 av = a4[q];
    float l0 = lg[q * 4], l1 = lg[q * 4 + 1], l2 = lg[q * 4 + 2], l3 = lg[q * 4 + 3];
    rs += (double)(av.x * spf32(-l0) + (1.f - av.x) * spf32(l0));
    rs += (double)(av.y * spf32(-l1) + (1.f - av.y) * spf32(l1));
    rs += (double)(av.z * spf32(-l2) + (1.f - av.z) * spf32(l2));
    rs += (double)(av.w * spf32(-l3) + (1.f - av.w) * spf32(l3));
  }
  sm[threadIdx.x] = rs;
  __syncthreads();
  for (int off = 128; off > 0; off >>= 1) {
    if (threadIdx.x < off) sm[threadIdx.x] += sm[threadIdx.x + off];
    __syncthreads();
  }
  if (threadIdx.x == 0) rc_part[blockIdx.x] = sm[0];
}

// ---- loss = mean(recon) * (1 + mean(log_probs)) ----
__global__ __launch_bounds__(256) void finalize(const double* __restrict__ lp_part,
                                                const double* __restrict__ rc_part, int nb,
                                                double invT, float* __restrict__ out0) {
  __shared__ double s1[256], s2[256];
  int tid = threadIdx.x;
  double a1 = 0, a2 = 0;
  for (int i = tid; i < nb; i += 256) { a1 += lp_part[i]; a2 += rc_part[i]; }
  s1[tid] = a1; s2[tid] = a2;
  __syncthreads();
  for (int off = 128; off > 0; off >>= 1) {
    if (tid < off) { s1[tid] += s1[tid + off]; s2[tid] += s2[tid + off]; }
    __syncthreads();
  }
  if (tid == 0) {
    double R = s1[0] * invT;
    double M = s2[0] * invT / 16.0;
    out0[0] = (float)(M + R * M);
  }
}

extern "C" void kernel_launch(void* const* d_in, const int* in_sizes, int n_in,
                              void* d_out, int out_size, void* d_ws, size_t ws_size,
                              hipStream_t stream) {
  const float* s   = (const float*)d_in[0];
  const float* a   = (const float*)d_in[1];
  const float* u   = (const float*)d_in[2];
  const float* W1  = (const float*)d_in[3];
  const float* b1  = (const float*)d_in[4];
  const float* W2  = (const float*)d_in[5];
  const float* b2  = (const float*)d_in[6];
  const float* W3  = (const float*)d_in[7];
  const float* b3  = (const float*)d_in[8];
  const float* Wp1 = (const float*)d_in[9];
  const float* bp1 = (const float*)d_in[10];
  const float* Wp2 = (const float*)d_in[11];
  const float* bp2 = (const float*)d_in[12];

  const double invT = 1.0 / (double)TT;

  // workspace carve: doubles first, then 16B-aligned floats, then ints
  double* ps_s   = (double*)d_ws;                 // NBR*64
  double* ps_a   = ps_s + (size_t)NBR * 64;       // NBR*16
  double* ps_h   = ps_a + (size_t)NBR * 16;       // NBT*32
  double* c1     = ps_h + (size_t)NBT * 32;       // 32
  double* c2     = c1 + 32;                       // 32
  double* c3     = c2 + 32;                       // 24 (17 used)
  double* lp     = c3 + 24;                       // NBT
  double* rc     = lp + NBT;                      // NBT
  float*  g      = (float*)(rc + NBT);            // TT*16 (16B aligned)
  float*  h      = g + (size_t)TT * 16;           // TT*32 (f32 h1)
  float*  lvals  = h + (size_t)TT * 32;           // TT
  int*    lastf  = (int*)(lvals + TT);            // NBT
  int*    carry  = lastf + NBT;                   // NBT
  int*    cnt    = carry + NBT;                   // 4 (1 used)
  int*    list   = cnt + 4;                       // LCAP

  float* out    = (float*)d_out;
  float* loss   = out;
  float* logits = out + 1;
  float* ha     = out + 1 + (size_t)TT * 16;
  float* hg     = ha + TT;

  hipMemsetAsync((void*)cnt, 0, sizeof(int), stream);
  reduce_sa<<<NBR, 256, 0, stream>>>(s, a, ps_s, ps_a);
  prep1<<<1, 640, 0, stream>>>(ps_s, ps_a, W1, b1, invT, c1);
  h1f<<<NBT, 256, 0, stream>>>(s, a, W1, c1, h, ps_h);
  prep2<<<1, 256, 0, stream>>>(ps_h, W2, b2, invT, c2);
  h2cs<<<NBT, 256, 0, stream>>>(h, W2, c2, ps_h);
  prep3<<<1, 256, 0, stream>>>(ps_h, W3, b3, invT, c3);
  outf<<<NBT, 256, 0, stream>>>(h, W2, c2, W3, c3, u, g, lvals, ha, cnt, list);
  fixk<<<64, 256, 0, stream>>>(s, a, u, W1, W2, W3, c1, c2, c3, cnt, list, ha);
  statsk<<<NBT, 256, 0, stream>>>(ha, lvals, lastf, lp);
  carry_scan<<<1, NBT, 0, stream>>>(lastf, carry, NBT);
  decode_kernel<<<NBT, 256, 0, stream>>>(s, a, g, Wp1, bp1, Wp2, bp2, ha, carry,
                                         logits, hg, rc);
  finalize<<<1, 256, 0, stream>>>(lp, rc, NBT, invT, loss);
}

// Round 20
// 297.288 us; speedup vs baseline: 2.0247x; 1.0502x over previous
//
#include <hip/hip_runtime.h>
#include <math.h>

// AlphaSegmenter. Structure = R17/R19 (passing, 312-317us).
// Spill-rule ledger (5 incidents R2/R5/R10/R12-13/R18): <=4 concurrent
// float4 loads on ~64-reg kernels; never bound below natural VGPR; never
// pass reg arrays by pointer; full-unroll reg-array-indexed loops.
// R20: final micro-opt — decode/statsk transcendentals switched to
// hardware-native __expf/__logf forms (softplus ~35->10 ops, tanh
// ~20->8 ops). Only logits/loss paths affected (thresholds 6e-2;
// perturbation ~1e-6). ha/margin/fix paths byte-identical.

#define TT 262144
#define NBT 1024   // TT/256 tile blocks
#define NBR 1024   // reduction blocks for s,a
#define MARGIN 2e-3f
#define LCAP 16384

__device__ __forceinline__ float spf32(float x) {             // softplus (accurate)
  return fmaxf(x, 0.f) + log1pf(expf(-fabsf(x)));
}
__device__ __forceinline__ float spf32f(float x) {            // softplus (fast, loss-only)
  return fmaxf(x, 0.f) + __logf(1.f + __expf(-fabsf(x)));
}
__device__ __forceinline__ float ftanhf(float x) {            // fast tanh (logits-only)
  float e = __expf(2.f * fabsf(x));                           // inf for big x -> t=1
  float t = 1.f - 2.f / (e + 1.f);
  return x >= 0.f ? t : -t;
}

// ---- inline f64 exp: Cody-Waite + degree-12 Horner, |x| <= 700 ----
__device__ __forceinline__ double exp64(double x) {
  const double LOG2E  = 1.4426950408889634074;
  const double LN2_HI = 6.93147180369123816490e-01;
  const double LN2_LO = 1.90821492927058770002e-10;
  double kd = rint(x * LOG2E);
  double r  = fma(-kd, LN2_HI, x);
  r = fma(-kd, LN2_LO, r);
  double p = 2.08767569878681e-9;
  p = fma(p, r, 2.505210838544172e-8);
  p = fma(p, r, 2.755731922398589e-7);
  p = fma(p, r, 2.7557319223985893e-6);
  p = fma(p, r, 2.48015873015873e-5);
  p = fma(p, r, 1.984126984126984e-4);
  p = fma(p, r, 1.388888888888889e-3);
  p = fma(p, r, 8.333333333333333e-3);
  p = fma(p, r, 4.1666666666666664e-2);
  p = fma(p, r, 1.6666666666666666e-1);
  p = fma(p, r, 0.5);
  p = fma(p, r, 1.0);
  p = fma(p, r, 1.0);
  int k = (int)kd;
  long long sb = ((long long)(k + 1023)) << 52;   // 2^k
  return p * __longlong_as_double(sb);
}

__device__ __forceinline__ double tanh64(double x) {
  double ax = fmin(fabs(x), 19.0);
  double e = exp64(2.0 * ax);
  double t = 1.0 - 2.0 / (e + 1.0);
  return x >= 0.0 ? t : -t;
}

// ---- vectorized deterministic column-sums of s[T,64], a[T,16] (f64) ----
__global__ __launch_bounds__(256) void reduce_sa(const float* __restrict__ s,
                                                 const float* __restrict__ a,
                                                 double* __restrict__ ps_s,
                                                 double* __restrict__ ps_a) {
  __shared__ double sm[256 * 4];
  int tid = threadIdx.x;
  {
    int cg = tid & 15;
    int rs = tid >> 4;
    double a0 = 0, a1 = 0, a2 = 0, a3 = 0;
    const float4* s4 = (const float4*)s;
    long row0 = (long)blockIdx.x * 16 + rs;
    long stride = (long)NBR * 16;
    for (long r = row0; r < TT; r += stride) {
      float4 v = s4[r * 16 + cg];
      a0 += (double)v.x; a1 += (double)v.y; a2 += (double)v.z; a3 += (double)v.w;
    }
    sm[tid * 4 + 0] = a0; sm[tid * 4 + 1] = a1;
    sm[tid * 4 + 2] = a2; sm[tid * 4 + 3] = a3;
    __syncthreads();
    if (tid < 64) {
      double ssum = 0.0;
#pragma unroll
      for (int r2 = 0; r2 < 16; ++r2) ssum += sm[r2 * 64 + tid];  // fixed order
      ps_s[(long)blockIdx.x * 64 + tid] = ssum;
    }
    __syncthreads();
  }
  {
    int cg = tid & 3;
    int rs = tid >> 2;
    double a0 = 0, a1 = 0, a2 = 0, a3 = 0;
    const float4* a4p = (const float4*)a;
    long row0 = (long)blockIdx.x * 64 + rs;
    long stride = (long)NBR * 64;
    for (long r = row0; r < TT; r += stride) {
      float4 v = a4p[r * 4 + cg];
      a0 += (double)v.x; a1 += (double)v.y; a2 += (double)v.z; a3 += (double)v.w;
    }
    sm[tid * 4 + 0] = a0; sm[tid * 4 + 1] = a1;
    sm[tid * 4 + 2] = a2; sm[tid * 4 + 3] = a3;
    __syncthreads();
    if (tid < 16) {
      double ssum = 0.0;
#pragma unroll
      for (int r2 = 0; r2 < 64; ++r2) ssum += sm[r2 * 16 + tid];  // fixed order
      ps_a[(long)blockIdx.x * 16 + tid] = ssum;
    }
  }
}

// ---- c1 = b1 + mean_x @ W1[80:160]; 1024 partials, 128-entry chains ----
__global__ __launch_bounds__(640) void prep1(const double* __restrict__ ps_s,
                                             const double* __restrict__ ps_a,
                                             const float* __restrict__ W1,
                                             const float* __restrict__ b1,
                                             double invT, double* __restrict__ c1) {
  __shared__ double partial[80][8];
  __shared__ double mx[80];
  int tid = threadIdx.x;
  int col = tid >> 3, sub = tid & 7;
  double ssum = 0.0;
  if (col < 64) {
#pragma unroll 8
    for (int i = 0; i < 128; ++i) ssum += ps_s[((long)sub * 128 + i) * 64 + col];
  } else {
    int c = col - 64;
#pragma unroll 8
    for (int i = 0; i < 128; ++i) ssum += ps_a[((long)sub * 128 + i) * 16 + c];
  }
  partial[col][sub] = ssum;
  __syncthreads();
  if (tid < 80) {
    double s = 0.0;
#pragma unroll
    for (int i = 0; i < 8; ++i) s += partial[tid][i];
    mx[tid] = s * invT;
  }
  __syncthreads();
  if (tid < 32) {
    double acc = (double)b1[tid];
    for (int j = 0; j < 80; ++j) acc += mx[j] * (double)W1[(80 + j) * 32 + tid];
    c1[tid] = acc;
  }
}

// ---- c2 = b2 + mean_h1 @ W2[32:64] (ps_h has NBT=1024 partials) ----
__global__ __launch_bounds__(256) void prep2(const double* __restrict__ ps,
                                             const float* __restrict__ W2,
                                             const float* __restrict__ b2,
                                             double invT, double* __restrict__ c2) {
  __shared__ double partial[32][8];
  __shared__ double mh[32];
  int tid = threadIdx.x;
  int col = tid >> 3, sub = tid & 7;
  double ssum = 0.0;
#pragma unroll
  for (int i = 0; i < 128; ++i) ssum += ps[(sub * 128 + i) * 32 + col];
  partial[col][sub] = ssum;
  __syncthreads();
  if (tid < 32) {
    double s = 0.0;
#pragma unroll
    for (int i = 0; i < 8; ++i) s += partial[tid][i];
    mh[tid] = s * invT;
  }
  __syncthreads();
  if (tid < 32) {
    double acc = (double)b2[tid];
    for (int j = 0; j < 32; ++j) acc += mh[j] * (double)W2[(32 + j) * 32 + tid];
    c2[tid] = acc;
  }
}

// ---- c3[k] = b3[32+k] + mean_h2 @ W3[32:64, 32+k], k=0..16 ----
__global__ __launch_bounds__(256) void prep3(const double* __restrict__ ps,
                                             const float* __restrict__ W3,
                                             const float* __restrict__ b3,
                                             double invT, double* __restrict__ c3) {
  __shared__ double partial[32][8];
  __shared__ double mh[32];
  int tid = threadIdx.x;
  int col = tid >> 3, sub = tid & 7;
  double ssum = 0.0;
#pragma unroll
  for (int i = 0; i < 128; ++i) ssum += ps[(sub * 128 + i) * 32 + col];
  partial[col][sub] = ssum;
  __syncthreads();
  if (tid < 32) {
    double s = 0.0;
#pragma unroll
    for (int i = 0; i < 8; ++i) s += partial[tid][i];
    mh[tid] = s * invT;
  }
  __syncthreads();
  if (tid < 17) {
    double acc = (double)b3[32 + tid];
    for (int j = 0; j < 32; ++j) acc += mh[j] * (double)W3[(32 + j) * 49 + 32 + tid];
    c3[tid] = acc;
  }
}

// h layout (f32): element (block b, col k, row r) at h[b*8192 + k*256 + r]

// ---- h1 = tanhf([s,a] @ W1[:80] + c1), f32; col-sum partials (inline) ----
__global__ __launch_bounds__(256, 4) void h1f(const float* __restrict__ s,
                                              const float* __restrict__ a,
                                              const float* __restrict__ W1,
                                              const double* __restrict__ c1,
                                              float* __restrict__ h,
                                              double* __restrict__ ps_h) {
  __shared__ float Wl[80 * 32];
  __shared__ double ws[4 * 32];
  for (int i = threadIdx.x; i < 80 * 32; i += 256) Wl[i] = W1[i];
  __syncthreads();
  long t = (long)blockIdx.x * 256 + threadIdx.x;
  float acc[32];
#pragma unroll
  for (int k = 0; k < 32; ++k) acc[k] = (float)c1[k];
  const float4* s4 = (const float4*)(s + t * 64);
#pragma unroll 2
  for (int q = 0; q < 16; ++q) {
    float4 v = s4[q];
    const float* w = &Wl[(q * 4) * 32];
#pragma unroll
    for (int k = 0; k < 32; ++k)
      acc[k] += v.x * w[k] + v.y * w[32 + k] + v.z * w[64 + k] + v.w * w[96 + k];
  }
  const float4* a4 = (const float4*)(a + t * 16);
#pragma unroll 2
  for (int q = 0; q < 4; ++q) {
    float4 v = a4[q];
    const float* w = &Wl[(64 + q * 4) * 32];
#pragma unroll
    for (int k = 0; k < 32; ++k)
      acc[k] += v.x * w[k] + v.y * w[32 + k] + v.z * w[64 + k] + v.w * w[96 + k];
  }
  float* o = h + (size_t)blockIdx.x * 8192 + threadIdx.x;
#pragma unroll
  for (int k = 0; k < 32; ++k) { acc[k] = tanhf(acc[k]); o[k * 256] = acc[k]; }
  int lane = threadIdx.x & 63, wave = threadIdx.x >> 6;
#pragma unroll
  for (int k = 0; k < 32; ++k) {           // in-scope f32 butterfly (no ptr!)
    float v = acc[k];
    v += __shfl_down(v, 32, 64); v += __shfl_down(v, 16, 64);
    v += __shfl_down(v, 8, 64);  v += __shfl_down(v, 4, 64);
    v += __shfl_down(v, 2, 64);  v += __shfl_down(v, 1, 64);
    if (lane == 0) ws[wave * 32 + k] = (double)v;
  }
  __syncthreads();
  if (threadIdx.x < 32) {
    double ssum = ws[threadIdx.x] + ws[32 + threadIdx.x] + ws[64 + threadIdx.x] +
                  ws[96 + threadIdx.x];
    ps_h[blockIdx.x * 32 + threadIdx.x] = ssum;
  }
}

// ---- h2 col-sums ONLY (h2 recomputed later in outf; no 33MB write) ----
__global__ __launch_bounds__(256, 4) void h2cs(const float* __restrict__ h1,
                                               const float* __restrict__ W2,
                                               const double* __restrict__ c2,
                                               double* __restrict__ ps_h) {
  __shared__ float Wl[32 * 32];
  __shared__ double ws[4 * 32];
  for (int i = threadIdx.x; i < 32 * 32; i += 256) Wl[i] = W2[i];
  __syncthreads();
  const float* x = h1 + (size_t)blockIdx.x * 8192 + threadIdx.x;
  float acc[32];
#pragma unroll
  for (int k = 0; k < 32; ++k) acc[k] = (float)c2[k];
#pragma unroll 4
  for (int j = 0; j < 32; ++j) {
    float xj = x[j * 256];
#pragma unroll
    for (int k = 0; k < 32; ++k) acc[k] += xj * Wl[j * 32 + k];
  }
#pragma unroll
  for (int k = 0; k < 32; ++k) acc[k] = tanhf(acc[k]);
  int lane = threadIdx.x & 63, wave = threadIdx.x >> 6;
#pragma unroll
  for (int k = 0; k < 32; ++k) {           // in-scope f32 butterfly (no ptr!)
    float v = acc[k];
    v += __shfl_down(v, 32, 64); v += __shfl_down(v, 16, 64);
    v += __shfl_down(v, 8, 64);  v += __shfl_down(v, 4, 64);
    v += __shfl_down(v, 2, 64);  v += __shfl_down(v, 1, 64);
    if (lane == 0) ws[wave * 32 + k] = (double)v;
  }
  __syncthreads();
  if (threadIdx.x < 32) {
    double ssum = ws[threadIdx.x] + ws[32 + threadIdx.x] + ws[64 + threadIdx.x] +
                  ws[96 + threadIdx.x];
    ps_h[blockIdx.x * 32 + threadIdx.x] = ssum;
  }
}

// ---- out: recompute h2 from h1 (bit-identical FMA order to h2cs), then
//      g (f32), l (f32), ha guess, ambiguous-row list ----
__global__ __launch_bounds__(256, 4) void outf(const float* __restrict__ h1,
                                               const float* __restrict__ W2,
                                               const double* __restrict__ c2,
                                               const float* __restrict__ W3,
                                               const double* __restrict__ c3,
                                               const float* __restrict__ u,
                                               float* __restrict__ g,
                                               float* __restrict__ lvals,
                                               float* __restrict__ ha,
                                               int* __restrict__ cnt,
                                               int* __restrict__ list) {
  __shared__ float W2l[32 * 32];
  __shared__ float W3l[32 * 17];
  for (int i = threadIdx.x; i < 32 * 32; i += 256) W2l[i] = W2[i];
  for (int i = threadIdx.x; i < 32 * 17; i += 256) {
    int j = i / 17, k = i - j * 17;
    W3l[i] = W3[j * 49 + 32 + k];
  }
  __syncthreads();
  long t = (long)blockIdx.x * 256 + threadIdx.x;
  const float* x = h1 + (size_t)blockIdx.x * 8192 + threadIdx.x;
  float h2r[32];
#pragma unroll
  for (int k = 0; k < 32; ++k) h2r[k] = (float)c2[k];
#pragma unroll 4
  for (int j = 0; j < 32; ++j) {
    float xj = x[j * 256];
#pragma unroll
    for (int k = 0; k < 32; ++k) h2r[k] += xj * W2l[j * 32 + k];
  }
#pragma unroll
  for (int k = 0; k < 32; ++k) h2r[k] = tanhf(h2r[k]);
  float acc[17];
#pragma unroll
  for (int k = 0; k < 17; ++k) acc[k] = (float)c3[k];
#pragma unroll
  for (int j = 0; j < 32; ++j) {            // FULL unroll: h2r is a reg array
    float xj = h2r[j];
#pragma unroll
    for (int k = 0; k < 17; ++k) acc[k] += xj * W3l[j * 17 + k];
  }
  float4* g4 = (float4*)(g + t * 16);
  float4 o0, o1, o2, o3;
  o0.x = acc[0];  o0.y = acc[1];  o0.z = acc[2];  o0.w = acc[3];
  o1.x = acc[4];  o1.y = acc[5];  o1.z = acc[6];  o1.w = acc[7];
  o2.x = acc[8];  o2.y = acc[9];  o2.z = acc[10]; o2.w = acc[11];
  o3.x = acc[12]; o3.y = acc[13]; o3.z = acc[14]; o3.w = acc[15];
  g4[0] = o0; g4[1] = o1; g4[2] = o2; g4[3] = o3;
  float l = acc[16];
  lvals[t] = l;
  float uu = u[t];
  // fired <=> u < sigmoid(l) <=> l > logit(u)
  float lu = (uu <= 0.f) ? -1e30f : (logf(uu) - logf(1.f - uu));
  float d = l - lu;
  ha[t] = (d > 0.f) ? 1.f : 0.f;
  if (fabsf(d) < MARGIN) {
    int i = atomicAdd(cnt, 1);
    if (i < LCAP) list[i] = (int)t;
  }
}

// ---- f64 recompute of ambiguous rows: one wave per row, no reg arrays ----
__global__ __launch_bounds__(256, 4) void fixk(const float* __restrict__ s,
                                               const float* __restrict__ a,
                                               const float* __restrict__ u,
                                               const float* __restrict__ W1,
                                               const float* __restrict__ W2,
                                               const float* __restrict__ W3,
                                               const double* __restrict__ c1,
                                               const double* __restrict__ c2,
                                               const double* __restrict__ c3,
                                               const int* __restrict__ cnt,
                                               const int* __restrict__ list,
                                               float* __restrict__ ha) {
  int n = *cnt;
  if (n > LCAP) n = LCAP;
  int lane = threadIdx.x & 63;
  int wid = (blockIdx.x * 256 + threadIdx.x) >> 6;
  const int nw = (64 * 256) >> 6;
  int col = lane & 31;
  for (int i = wid; i < n; i += nw) {
    int row = list[i];
    double acc = c1[col];
    for (int j = 0; j < 64; ++j)
      acc += (double)s[(size_t)row * 64 + j] * (double)W1[j * 32 + col];
    for (int j = 0; j < 16; ++j)
      acc += (double)a[(size_t)row * 16 + j] * (double)W1[(64 + j) * 32 + col];
    double h1v = tanh64(acc);
    double acc2 = c2[col];
    for (int j = 0; j < 32; ++j)
      acc2 += __shfl(h1v, j, 64) * (double)W2[j * 32 + col];
    double h2v = tanh64(acc2);
    double term = h2v * (double)W3[col * 49 + 48];
    term += __shfl_down(term, 16, 64);
    term += __shfl_down(term, 8, 64);
    term += __shfl_down(term, 4, 64);
    term += __shfl_down(term, 2, 64);
    term += __shfl_down(term, 1, 64);
    if (lane == 0) {
      double l = c3[16] + term;
      double lc = fmin(fmax(l, -700.0), 700.0);
      double alpha = 1.0 / (1.0 + exp64(-lc));
      ha[row] = (((double)u[row]) < alpha) ? 1.f : 0.f;
    }
  }
}

// ---- post-fix stats: lp partials + per-block last-fired ----
__global__ __launch_bounds__(256, 4) void statsk(const float* __restrict__ ha,
                                                 const float* __restrict__ lvals,
                                                 int* __restrict__ lastf,
                                                 double* __restrict__ lp_part) {
  __shared__ double sm[256];
  __shared__ unsigned long long wm[4];
  long t = (long)blockIdx.x * 256 + threadIdx.x;
  bool fired = ha[t] > 0.5f;
  float lf = lvals[t];
  sm[threadIdx.x] = (double)(fired ? -spf32f(-lf) : -spf32f(lf));
  unsigned long long bm = __ballot(fired ? 1 : 0);
  if ((threadIdx.x & 63) == 0) wm[threadIdx.x >> 6] = bm;
  __syncthreads();
  for (int off = 128; off > 0; off >>= 1) {
    if (threadIdx.x < off) sm[threadIdx.x] += sm[threadIdx.x + off];
    __syncthreads();
  }
  if (threadIdx.x == 0) {
    lp_part[blockIdx.x] = sm[0];
    int last = -1;
#pragma unroll
    for (int w = 3; w >= 0; --w) {
      if (last < 0 && wm[w])
        last = (int)((long)blockIdx.x * 256 + w * 64 + (63 - __builtin_clzll(wm[w])));
    }
    lastf[blockIdx.x] = last;
  }
}

// ---- exclusive max-scan over per-block last-fired indices ----
__global__ __launch_bounds__(1024) void carry_scan(const int* __restrict__ lastf,
                                                   int* __restrict__ carry, int n) {
  __shared__ int sm[1024];
  int tid = threadIdx.x;
  sm[tid] = (tid < n) ? lastf[tid] : -1;
  __syncthreads();
  for (int off = 1; off < n; off <<= 1) {
    int v = sm[tid];
    int o = (tid >= off) ? sm[tid - off] : -1;
    __syncthreads();
    sm[tid] = v > o ? v : o;
    __syncthreads();
  }
  if (tid < n) carry[tid] = (tid == 0) ? -1 : sm[tid - 1];
}

// ---- scan-combine, hard_g gather, decode MLP, logits, BCE partials ----
__global__ __launch_bounds__(256, 4) void decode_kernel(
    const float* __restrict__ s, const float* __restrict__ a, const float* __restrict__ g,
    const float* __restrict__ Wp1, const float* __restrict__ bp1, const float* __restrict__ Wp2,
    const float* __restrict__ bp2, const float* __restrict__ ha, const int* __restrict__ carry,
    float* __restrict__ logits, float* __restrict__ hardg, double* __restrict__ rc_part) {
  __shared__ float W1l[80 * 32];
  __shared__ float W2l[32 * 16];
  __shared__ int wlast[4];
  __shared__ double sm[256];
  long t = (long)blockIdx.x * 256 + threadIdx.x;
  bool fired = ha[t] > 0.5f;
  unsigned long long m = __ballot(fired ? 1 : 0);
  int wave = threadIdx.x >> 6, lane = threadIdx.x & 63;
  if (lane == 0)
    wlast[wave] = m ? (int)((long)blockIdx.x * 256 + wave * 64 + (63 - __builtin_clzll(m))) : -1;
  for (int i = threadIdx.x; i < 80 * 32; i += 256) W1l[i] = Wp1[i];
  for (int i = threadIdx.x; i < 32 * 16; i += 256) W2l[i] = Wp2[i];
  __syncthreads();
  unsigned long long pm = m & (~0ULL >> (63 - lane));
  int idx = pm ? (int)((long)blockIdx.x * 256 + wave * 64 + (63 - __builtin_clzll(pm))) : -1;
#pragma unroll
  for (int w = 0; w < 4; ++w)
    if (w < wave && wlast[w] > idx) idx = wlast[w];
  int cr = carry[blockIdx.x];
  if (cr > idx) idx = cr;
  float msk = idx >= 0 ? 1.f : 0.f;
  const float4* g4 = (const float4*)(g + (long)(idx >= 0 ? idx : 0) * 16);
  float4 v0 = g4[0], v1 = g4[1], v2 = g4[2], v3 = g4[3];
  float hg0  = msk * v0.x, hg1  = msk * v0.y, hg2  = msk * v0.z, hg3  = msk * v0.w;
  float hg4  = msk * v1.x, hg5  = msk * v1.y, hg6  = msk * v1.z, hg7  = msk * v1.w;
  float hg8  = msk * v2.x, hg9  = msk * v2.y, hg10 = msk * v2.z, hg11 = msk * v2.w;
  float hg12 = msk * v3.x, hg13 = msk * v3.y, hg14 = msk * v3.z, hg15 = msk * v3.w;
  hardg[t * 16 + 0]  = hg0;  hardg[t * 16 + 1]  = hg1;
  hardg[t * 16 + 2]  = hg2;  hardg[t * 16 + 3]  = hg3;
  hardg[t * 16 + 4]  = hg4;  hardg[t * 16 + 5]  = hg5;
  hardg[t * 16 + 6]  = hg6;  hardg[t * 16 + 7]  = hg7;
  hardg[t * 16 + 8]  = hg8;  hardg[t * 16 + 9]  = hg9;
  hardg[t * 16 + 10] = hg10; hardg[t * 16 + 11] = hg11;
  hardg[t * 16 + 12] = hg12; hardg[t * 16 + 13] = hg13;
  hardg[t * 16 + 14] = hg14; hardg[t * 16 + 15] = hg15;
  float acc[32];
#pragma unroll
  for (int k = 0; k < 32; ++k) {          // consume hg first (live-range, R6)
    float v = bp1[k];
    v += hg0  * W1l[(64 + 0)  * 32 + k];  v += hg1  * W1l[(64 + 1)  * 32 + k];
    v += hg2  * W1l[(64 + 2)  * 32 + k];  v += hg3  * W1l[(64 + 3)  * 32 + k];
    v += hg4  * W1l[(64 + 4)  * 32 + k];  v += hg5  * W1l[(64 + 5)  * 32 + k];
    v += hg6  * W1l[(64 + 6)  * 32 + k];  v += hg7  * W1l[(64 + 7)  * 32 + k];
    v += hg8  * W1l[(64 + 8)  * 32 + k];  v += hg9  * W1l[(64 + 9)  * 32 + k];
    v += hg10 * W1l[(64 + 10) * 32 + k];  v += hg11 * W1l[(64 + 11) * 32 + k];
    v += hg12 * W1l[(64 + 12) * 32 + k];  v += hg13 * W1l[(64 + 13) * 32 + k];
    v += hg14 * W1l[(64 + 14) * 32 + k];  v += hg15 * W1l[(64 + 15) * 32 + k];
    acc[k] = v;
  }
  const float4* s4 = (const float4*)(s + t * 64);
#pragma unroll 4
  for (int q = 0; q < 16; ++q) {
    float4 v = s4[q];
    const float* w = &W1l[(q * 4) * 32];
#pragma unroll
    for (int k = 0; k < 32; ++k)
      acc[k] += v.x * w[k] + v.y * w[32 + k] + v.z * w[64 + k] + v.w * w[96 + k];
  }
#pragma unroll
  for (int k = 0; k < 32; ++k) acc[k] = ftanhf(acc[k]);
  float lg[16];
#pragma unroll
  for (int k = 0; k < 16; ++k) lg[k] = bp2[k];
#pragma unroll
  for (int j = 0; j < 32; ++j) {
    float hj = acc[j];
    const float* w = &W2l[j * 16];
#pragma unroll
    for (int k = 0; k < 16; ++k) lg[k] += hj * w[k];
  }
#pragma unroll
  for (int k = 0; k < 16; ++k) logits[t * 16 + k] = lg[k];
  const float4* a4 = (const float4*)(a + t * 16);
  double rs = 0.0;
#pragma unroll
  for (int q = 0; q < 4; ++q) {
    float4 av = a4[q];
    float l0 = lg[q * 4], l1 = lg[q * 4 + 1], l2 = lg[q * 4 + 2], l3 = lg[q * 4 + 3];
    rs += (double)(av.x * spf32f(-l0) + (1.f - av.x) * spf32f(l0));
    rs += (double)(av.y * spf32f(-l1) + (1.f - av.y) * spf32f(l1));
    rs += (double)(av.z * spf32f(-l2) + (1.f - av.z) * spf32f(l2));
    rs += (double)(av.w * spf32f(-l3) + (1.f - av.w) * spf32f(l3));
  }
  sm[threadIdx.x] = rs;
  __syncthreads();
  for (int off = 128; off > 0; off >>= 1) {
    if (threadIdx.x < off) sm[threadIdx.x] += sm[threadIdx.x + off];
    __syncthreads();
  }
  if (threadIdx.x == 0) rc_part[blockIdx.x] = sm[0];
}

// ---- loss = mean(recon) * (1 + mean(log_probs)) ----
__global__ __launch_bounds__(256) void finalize(const double* __restrict__ lp_part,
                                                const double* __restrict__ rc_part, int nb,
                                                double invT, float* __restrict__ out0) {
  __shared__ double s1[256], s2[256];
  int tid = threadIdx.x;
  double a1 = 0, a2 = 0;
  for (int i = tid; i < nb; i += 256) { a1 += lp_part[i]; a2 += rc_part[i]; }
  s1[tid] = a1; s2[tid] = a2;
  __syncthreads();
  for (int off = 128; off > 0; off >>= 1) {
    if (tid < off) { s1[tid] += s1[tid + off]; s2[tid] += s2[tid + off]; }
    __syncthreads();
  }
  if (tid == 0) {
    double R = s1[0] * invT;
    double M = s2[0] * invT / 16.0;
    out0[0] = (float)(M + R * M);
  }
}

extern "C" void kernel_launch(void* const* d_in, const int* in_sizes, int n_in,
                              void* d_out, int out_size, void* d_ws, size_t ws_size,
                              hipStream_t stream) {
  const float* s   = (const float*)d_in[0];
  const float* a   = (const float*)d_in[1];
  const float* u   = (const float*)d_in[2];
  const float* W1  = (const float*)d_in[3];
  const float* b1  = (const float*)d_in[4];
  const float* W2  = (const float*)d_in[5];
  const float* b2  = (const float*)d_in[6];
  const float* W3  = (const float*)d_in[7];
  const float* b3  = (const float*)d_in[8];
  const float* Wp1 = (const float*)d_in[9];
  const float* bp1 = (const float*)d_in[10];
  const float* Wp2 = (const float*)d_in[11];
  const float* bp2 = (const float*)d_in[12];

  const double invT = 1.0 / (double)TT;

  // workspace carve: doubles first, then 16B-aligned floats, then ints
  double* ps_s   = (double*)d_ws;                 // NBR*64
  double* ps_a   = ps_s + (size_t)NBR * 64;       // NBR*16
  double* ps_h   = ps_a + (size_t)NBR * 16;       // NBT*32
  double* c1     = ps_h + (size_t)NBT * 32;       // 32
  double* c2     = c1 + 32;                       // 32
  double* c3     = c2 + 32;                       // 24 (17 used)
  double* lp     = c3 + 24;                       // NBT
  double* rc     = lp + NBT;                      // NBT
  float*  g      = (float*)(rc + NBT);            // TT*16 (16B aligned)
  float*  h      = g + (size_t)TT * 16;           // TT*32 (f32 h1)
  float*  lvals  = h + (size_t)TT * 32;           // TT
  int*    lastf  = (int*)(lvals + TT);            // NBT
  int*    carry  = lastf + NBT;                   // NBT
  int*    cnt    = carry + NBT;                   // 4 (1 used)
  int*    list   = cnt + 4;                       // LCAP

  float* out    = (float*)d_out;
  float* loss   = out;
  float* logits = out + 1;
  float* ha     = out + 1 + (size_t)TT * 16;
  float* hg     = ha + TT;

  hipMemsetAsync((void*)cnt, 0, sizeof(int), stream);
  reduce_sa<<<NBR, 256, 0, stream>>>(s, a, ps_s, ps_a);
  prep1<<<1, 640, 0, stream>>>(ps_s, ps_a, W1, b1, invT, c1);
  h1f<<<NBT, 256, 0, stream>>>(s, a, W1, c1, h, ps_h);
  prep2<<<1, 256, 0, stream>>>(ps_h, W2, b2, invT, c2);
  h2cs<<<NBT, 256, 0, stream>>>(h, W2, c2, ps_h);
  prep3<<<1, 256, 0, stream>>>(ps_h, W3, b3, invT, c3);
  outf<<<NBT, 256, 0, stream>>>(h, W2, c2, W3, c3, u, g, lvals, ha, cnt, list);
  fixk<<<64, 256, 0, stream>>>(s, a, u, W1, W2, W3, c1, c2, c3, cnt, list, ha);
  statsk<<<NBT, 256, 0, stream>>>(ha, lvals, lastf, lp);
  carry_scan<<<1, NBT, 0, stream>>>(lastf, carry, NBT);
  decode_kernel<<<NBT, 256, 0, stream>>>(s, a, g, Wp1, bp1, Wp2, bp2, ha, carry,
                                         logits, hg, rc);
  finalize<<<1, 256, 0, stream>>>(lp, rc, NBT, invT, loss);
}